// Round 1
// baseline (69.850 us; speedup 1.0000x reference)
//
#include <hip/hip_runtime.h>

#define NROWS 500000
#define NCOLS 80
// NV = number of float4 chunks in logits
#define NV (NROWS * NCOLS / 4)

// ---------------------------------------------------------------------------
// Pass 1: M = max over fg rows of iou.  targets is (N,2) interleaved -> float2.
// All candidate values are >= 0, so float bit pattern orders as unsigned int.
// ---------------------------------------------------------------------------
__global__ void max_iou_kernel(const float2* __restrict__ targets,
                               float* __restrict__ m_out, int n) {
    int tid = blockIdx.x * blockDim.x + threadIdx.x;
    int stride = gridDim.x * blockDim.x;
    float vmax = 0.0f;
    for (int i = tid; i < n; i += stride) {
        float2 t = targets[i];
        int c = (int)t.x - 1;
        if (c >= 0) vmax = fmaxf(vmax, t.y);
    }
    // wave64 butterfly reduce
    #pragma unroll
    for (int off = 32; off > 0; off >>= 1)
        vmax = fmaxf(vmax, __shfl_xor(vmax, off));
    __shared__ float smax[4];
    int lane = threadIdx.x & 63;
    int wid  = threadIdx.x >> 6;
    if (lane == 0) smax[wid] = vmax;
    __syncthreads();
    if (threadIdx.x == 0) {
        float b = smax[0];
        for (int w = 1; w < (int)(blockDim.x >> 6); ++w) b = fmaxf(b, smax[w]);
        atomicMax((unsigned int*)m_out, __float_as_uint(b));
    }
}

// ---------------------------------------------------------------------------
// Pass 2: sum over all elements.
//   base (label==0): 0.75*(softplus(x) - sigmoid(x))   [pos is always false]
//   fg element (col == cls): full pos/neg branch with L = iou / M
// Stable softplus from e = exp(-|x|):
//   rt = 1/(1+e);  p = x>=0 ? rt : 1-rt;  sp = max(x,0) + log(1+e);  sp(-x)=sp-x
// ---------------------------------------------------------------------------
__global__ void loss_kernel(const float4* __restrict__ logits4,
                            const float2* __restrict__ targets,
                            const float* __restrict__ m_ptr,
                            float* __restrict__ out) {
    const float invM = 1.0f / m_ptr[0];
    unsigned tid = blockIdx.x * blockDim.x + threadIdx.x;
    unsigned stride = gridDim.x * blockDim.x;
    float acc = 0.0f;
    for (unsigned v = tid; v < (unsigned)NV; v += stride) {
        unsigned r = v / 20u;           // row (magic-mul division)
        unsigned q = v - r * 20u;       // float4 index within row
        int j0 = (int)(q * 4u);         // first column of this float4
        float4 x4 = logits4[v];
        float2 t  = targets[r];         // broadcast within 20 adjacent threads
        int   c   = (int)t.x - 1;       // -1..79 ; never matches when -1
        float L   = t.y * invM;

        float xs[4] = {x4.x, x4.y, x4.z, x4.w};
        #pragma unroll
        for (int k = 0; k < 4; ++k) {
            float x  = xs[k];
            float ax = fabsf(x);
            float e  = __expf(-ax);
            float rt = __frcp_rn(1.0f + e);
            float p  = (x >= 0.0f) ? rt : 1.0f - rt;
            float sp = fmaxf(x, 0.0f) + __logf(1.0f + e);
            float term;
            if (j0 + k == c) {
                float spn = sp - x;               // softplus(-x)
                bool  pos = (p <= L);
                term = pos ? 0.25f * (spn * L + (p - L))
                           : 0.75f * (sp * (1.0f - L) + (L - p));
            } else {
                term = 0.75f * (sp - p);
            }
            acc += term;
        }
    }
    // wave64 butterfly reduce
    #pragma unroll
    for (int off = 32; off > 0; off >>= 1)
        acc += __shfl_xor(acc, off);
    __shared__ float ssum[4];
    int lane = threadIdx.x & 63;
    int wid  = threadIdx.x >> 6;
    if (lane == 0) ssum[wid] = acc;
    __syncthreads();
    if (threadIdx.x == 0) {
        float b = 0.0f;
        for (int w = 0; w < (int)(blockDim.x >> 6); ++w) b += ssum[w];
        atomicAdd(out, b);
    }
}

extern "C" void kernel_launch(void* const* d_in, const int* in_sizes, int n_in,
                              void* d_out, int out_size, void* d_ws, size_t ws_size,
                              hipStream_t stream) {
    const float* logits  = (const float*)d_in[0];   // (N, C) f32
    const float* targets = (const float*)d_in[1];   // (N, 2) f32
    float* out = (float*)d_out;                     // scalar f32
    float* m   = (float*)d_ws;                      // 4B scratch: global max

    hipMemsetAsync(out, 0, sizeof(float), stream);
    hipMemsetAsync(m,   0, sizeof(float), stream);

    max_iou_kernel<<<512, 256, 0, stream>>>((const float2*)targets, m, NROWS);
    loss_kernel<<<2048, 256, 0, stream>>>((const float4*)logits,
                                          (const float2*)targets, m, out);
}